// Round 6
// baseline (190.157 us; speedup 1.0000x reference)
//
#include <hip/hip_runtime.h>
#include <stdint.h>
#include <stddef.h>

// Problem: B=4, C=256, CR=32, H=W=64, N=4096
#define Bn 4
#define Cn 256
#define CRn 32
#define Nn 4096

typedef __attribute__((ext_vector_type(8))) short short8v;  // 8 bf16 (4 VGPR)
typedef __attribute__((ext_vector_type(4))) float f32x4;

__device__ __forceinline__ unsigned short f2bf(float f) {
  unsigned int u = __float_as_uint(f);
  u += 0x7FFFu + ((u >> 16) & 1u);   // RNE
  return (unsigned short)(u >> 16);
}

// ---------------- kernel 0: cast W (Wq|Wk|Wv rows) -> Wb [320][256] bf16 ----------------
__global__ void __launch_bounds__(256) k_wcast(const float* __restrict__ Wq,
                                               const float* __restrict__ Wk,
                                               const float* __restrict__ Wv,
                                               unsigned short* __restrict__ Wb) {
  int idx = (blockIdx.x * 256 + threadIdx.x) * 4;   // 80 blocks -> 81920 elems
  int row = idx >> 8, cc = idx & 255;
  const float* src = (row < 32) ? &Wq[row * 256 + cc]
                   : (row < 64) ? &Wk[(row - 32) * 256 + cc]
                                : &Wv[(row - 64) * 256 + cc];
  float4 f = *reinterpret_cast<const float4*>(src);
  ushort4 o;
  o.x = f2bf(f.x); o.y = f2bf(f.y); o.z = f2bf(f.z); o.w = f2bf(f.w);
  *reinterpret_cast<ushort4*>(&Wb[idx]) = o;
}

// ---------------- kernel 1: fused transpose + projections ----------------
// Per block (nt, b): stage x[b][:, nt*64..+63] transposed to LDS as bf16,
// then D[n][r] = sum_c xT[n][c] * Wb[r][c] for all 320 W-rows.
// 8 waves = nw(4, n-quarters) x rh(2, W-row halves of 160).
__global__ void __launch_bounds__(512) k_proj(const unsigned short* __restrict__ Wb,
                                              const float* __restrict__ x,
                                              unsigned short* __restrict__ Qt,
                                              unsigned short* __restrict__ Kt,
                                              unsigned short* __restrict__ V) {
  __shared__ __align__(16) unsigned char smem[50432];
  unsigned short* xs = (unsigned short*)smem;            // [64 n][264] bf16 (33792 B)
  float* xf = (float*)(smem + 33792);                    // [64 c][65] f32  (16640 B)
  unsigned short* vb = (unsigned short*)smem;            // [256 c][72] bf16 (36864 B, reuse)
  const int t  = threadIdx.x;
  const int nt = blockIdx.x, b = blockIdx.y;
  const int li = t & 15, cr = t >> 4;                     // li: n-quad, cr: 0..31

  // ---- stage x^T tile in 4 rounds of 64 channels ----
  for (int ct = 0; ct < 4; ++ct) {
    if (ct) __syncthreads();        // xf reuse
#pragma unroll
    for (int p = 0; p < 2; ++p) {
      int c = cr + (p << 5);        // 0..63 local channel
      float4 f = *reinterpret_cast<const float4*>(
          &x[(((size_t)((b << 8) + (ct << 6) + c)) << 12) + (nt << 6) + (li << 2)]);
      xf[c * 65 + (li << 2) + 0] = f.x;
      xf[c * 65 + (li << 2) + 1] = f.y;
      xf[c * 65 + (li << 2) + 2] = f.z;
      xf[c * 65 + (li << 2) + 3] = f.w;
    }
    __syncthreads();
#pragma unroll
    for (int p = 0; p < 2; ++p) {
      int nl = cr + (p << 5);
      int cq = li << 2;
      ushort4 o;
      o.x = f2bf(xf[(cq + 0) * 65 + nl]);
      o.y = f2bf(xf[(cq + 1) * 65 + nl]);
      o.z = f2bf(xf[(cq + 2) * 65 + nl]);
      o.w = f2bf(xf[(cq + 3) * 65 + nl]);
      *reinterpret_cast<ushort4*>(&xs[nl * 264 + (ct << 6) + cq]) = o;
    }
  }
  __syncthreads();

  const int lane = t & 63, w = t >> 6, col = lane & 15, hi = lane >> 4;
  const int nw = w & 3, rh = w >> 2;
  f32x4 zero4 = {0.f, 0.f, 0.f, 0.f};
  f32x4 acc[10];
#pragma unroll
  for (int rc = 0; rc < 10; ++rc) acc[rc] = zero4;

#pragma unroll
  for (int ks = 0; ks < 8; ++ks) {
    short8v af = *reinterpret_cast<const short8v*>(
        &xs[((nw << 4) + col) * 264 + (ks << 5) + (hi << 3)]);
#pragma unroll
    for (int rc = 0; rc < 10; ++rc) {
      short8v bf = *reinterpret_cast<const short8v*>(
          Wb + (((size_t)(rh * 160 + (rc << 4) + col)) << 8) + (ks << 5) + (hi << 3));
      acc[rc] = __builtin_amdgcn_mfma_f32_16x16x32_bf16(af, bf, acc[rc], 0, 0, 0);
    }
  }

  // Q/K outputs (rh==0, W-rows 0..63): [n][32] layouts
  if (rh == 0) {
#pragma unroll
    for (int rc = 0; rc < 2; ++rc)
#pragma unroll
      for (int r = 0; r < 4; ++r) {
        int n = (nt << 6) + (nw << 4) + (hi << 2) + r;
        Qt[(((size_t)((b << 12) + n)) << 5) + (rc << 4) + col] = f2bf(acc[rc][r]);
      }
#pragma unroll
    for (int rc = 2; rc < 4; ++rc)
#pragma unroll
      for (int r = 0; r < 4; ++r) {
        int n = (nt << 6) + (nw << 4) + (hi << 2) + r;
        Kt[(((size_t)((b << 12) + n)) << 5) + ((rc - 2) << 4) + col] = f2bf(acc[rc][r]);
      }
  }
  __syncthreads();   // all xs reads done; vb aliases smem

  // V channels -> vb[c][n] (transpose buffer)
  {
    const int rcStart = (rh == 0) ? 4 : 0;
    const int nb = (nw << 4) + (hi << 2);
#pragma unroll
    for (int rc = 0; rc < 10; ++rc) {
      if (rc < rcStart) continue;
      int c = rh * 160 + (rc << 4) + col - 64;
#pragma unroll
      for (int r = 0; r < 4; ++r)
        vb[c * 72 + nb + r] = f2bf(acc[rc][r]);
    }
  }
  __syncthreads();

  // coalesced V store: 2048 x 16B, 8 lanes cover one 128B channel row
#pragma unroll
  for (int p = 0; p < 4; ++p) {
    int idx = (p << 9) + t;
    int c = idx >> 3, off = idx & 7;
    int offp = off ^ (c & 7);   // LDS bank spread; same 128B global segment
    int4 dv = *reinterpret_cast<const int4*>(&vb[c * 72 + (offp << 3)]);
    *reinterpret_cast<int4*>(
        &V[(((size_t)((b << 8) + c)) << 12) + (nt << 6) + (offp << 3)]) = dv;
  }
}

// ---------------- kernel 2: flash attention ----------------
// grid 512 = (b 4) x (ch 2, channel half) x (qt 64). 512 thr, 8 waves.
// wave w: g = w>>2 (KV half: kt in [g*32, g*32+32)), wg = w&3 (softmax cols wg*16..+15,
// channel slice cBase = ch*128 + wg*32). K and V fragments direct from L2 into regs.
// One lgkm-only barrier per phase; Pt/Sc double-buffered by phase parity.
__global__ void __launch_bounds__(512, 4) k_attn(const unsigned short* __restrict__ Qt,
                                                 const unsigned short* __restrict__ Kt,
                                                 const unsigned short* __restrict__ Vv,
                                                 const float* __restrict__ x,
                                                 float* __restrict__ out) {
  __shared__ unsigned short Qs[64][40];
  __shared__ __align__(16) unsigned short Pt[2][2][64 * 64];  // [g][parity], 16B-unit XOR swz
  __shared__ float Sc[2][2][64];
  __shared__ float Mm[2][64], Ll[2][64];
  __shared__ float Ob[4][16][64];

  const int t = threadIdx.x, bx = blockIdx.x;
  const int xcd = bx & 7;                 // XCD-locality: fixed (b,ch) per XCD
  const int b = xcd >> 1, ch = xcd & 1;
  const int qt = bx >> 3;                 // 0..63
  const int lane = t & 63, w = t >> 6, col = lane & 15, hi = lane >> 4;
  const int g = w >> 2, wg = w & 3;
  const int cBase = (ch << 7) + (wg << 5);

  if (t < 256) {  // stage Q tile [64][32]
    const int mr = t >> 2, u = t & 3;
    int4 d = *reinterpret_cast<const int4*>(
        Qt + (((size_t)((b << 12) + (qt << 6) + mr)) << 5) + (u << 3));
    *reinterpret_cast<int4*>(&Qs[mr][u << 3]) = d;
  }

  const unsigned short* KtB = Kt + (((size_t)(b << 12)) << 5);
  const unsigned short* VvB = Vv + (((size_t)((b << 8) + cBase)) << 12);

  const int kt0 = g << 5;
  int m0 = kt0 << 6;
  short8v kf[4], vf[4];
#pragma unroll
  for (int mb = 0; mb < 4; ++mb)
    kf[mb] = *reinterpret_cast<const short8v*>(
        KtB + (((size_t)(m0 + (mb << 4) + col)) << 5) + (hi << 3));
#pragma unroll
  for (int ks = 0; ks < 2; ++ks)
#pragma unroll
    for (int cb = 0; cb < 2; ++cb)
      vf[(ks << 1) + cb] = *reinterpret_cast<const short8v*>(
          VvB + (((size_t)((cb << 4) + col)) << 12) + m0 + (ks << 5) + (hi << 3));
  __syncthreads();
  const short8v qf = *reinterpret_cast<const short8v*>(&Qs[(wg << 4) + col][hi << 3]);

  f32x4 zero4 = {0.f, 0.f, 0.f, 0.f};
  f32x4 o_acc[2][4];
#pragma unroll
  for (int cb = 0; cb < 2; ++cb)
#pragma unroll
    for (int nc = 0; nc < 4; ++nc) o_acc[cb][nc] = zero4;
  float m_run = -3e38f, l_run = 0.f;

#pragma unroll 1
  for (int i = 0; i < 32; ++i) {
    const int p = i & 1;
    const int iNext = (i < 31) ? (i + 1) : 31;
    const int mN = (kt0 + iNext) << 6;

    // ---- S^T slice: rows m (4 chunks), cols n = wg*16..+15 ----
    f32x4 s_acc[4];
#pragma unroll
    for (int mb = 0; mb < 4; ++mb)
      s_acc[mb] = __builtin_amdgcn_mfma_f32_16x16x32_bf16(kf[mb], qf, zero4, 0, 0, 0);
    // K prefetch next tile (WAR on kf orders after the MFMAs)
#pragma unroll
    for (int mb = 0; mb < 4; ++mb)
      kf[mb] = *reinterpret_cast<const short8v*>(
          KtB + (((size_t)(mN + (mb << 4) + col)) << 5) + (hi << 3));

    // ---- wave-local online softmax (column n = qt*64 + wg*16 + col) ----
    float tm = -3e38f;
#pragma unroll
    for (int mb = 0; mb < 4; ++mb)
#pragma unroll
      for (int r = 0; r < 4; ++r) tm = fmaxf(tm, s_acc[mb][r]);
    tm = fmaxf(tm, __shfl_xor(tm, 16));
    tm = fmaxf(tm, __shfl_xor(tm, 32));
    float mn = fmaxf(m_run, tm);
    float sc = __expf(m_run - mn);
    m_run = mn;
    float ps = 0.f;
#pragma unroll
    for (int mb = 0; mb < 4; ++mb)
#pragma unroll
      for (int r = 0; r < 4; ++r) {
        float pv = __expf(s_acc[mb][r] - mn);
        s_acc[mb][r] = pv;
        ps += pv;
      }
    ps += __shfl_xor(ps, 16);
    ps += __shfl_xor(ps, 32);
    l_run = l_run * sc + ps;
    if (hi == 0) Sc[g][p][(wg << 4) + col] = sc;
    // P^T bf16 -> Pt[g][p], rows n-local, 16B-unit XOR swizzle on m
#pragma unroll
    for (int mb = 0; mb < 4; ++mb) {
      uint2 pk2;
      pk2.x = (unsigned)f2bf(s_acc[mb][0]) | ((unsigned)f2bf(s_acc[mb][1]) << 16);
      pk2.y = (unsigned)f2bf(s_acc[mb][2]) | ((unsigned)f2bf(s_acc[mb][3]) << 16);
      int uu = (mb << 1) + (hi >> 1);
      int up = uu ^ (col & 7);
      *reinterpret_cast<uint2*>(
          &Pt[g][p][(((wg << 4) + col) << 6) + (up << 3) + ((hi & 1) << 2)]) = pk2;
    }

    // ---- single barrier: drain LDS writes only; V/K loads stay in flight ----
    asm volatile("s_waitcnt lgkmcnt(0)" ::: "memory");
    __builtin_amdgcn_s_barrier();

    // ---- rescale + PV (Pt[g][p], current vf) ----
    float scl[4];
#pragma unroll
    for (int nc = 0; nc < 4; ++nc) scl[nc] = Sc[g][p][(nc << 4) + col];
#pragma unroll
    for (int cb = 0; cb < 2; ++cb)
#pragma unroll
      for (int nc = 0; nc < 4; ++nc) o_acc[cb][nc] *= scl[nc];
#pragma unroll
    for (int ks = 0; ks < 2; ++ks) {
      short8v pb[4];
      int up2 = ((ks << 2) + hi) ^ (col & 7);
#pragma unroll
      for (int nc = 0; nc < 4; ++nc)
        pb[nc] = *reinterpret_cast<const short8v*>(
            &Pt[g][p][(((nc << 4) + col) << 6) + (up2 << 3)]);
#pragma unroll
      for (int cb = 0; cb < 2; ++cb)
#pragma unroll
        for (int nc = 0; nc < 4; ++nc)
          o_acc[cb][nc] = __builtin_amdgcn_mfma_f32_16x16x32_bf16(
              vf[(ks << 1) + cb], pb[nc], o_acc[cb][nc], 0, 0, 0);
    }
    // V prefetch next tile (WAR on vf orders after the MFMAs; in flight across barrier)
#pragma unroll
    for (int ks = 0; ks < 2; ++ks)
#pragma unroll
      for (int cb = 0; cb < 2; ++cb)
        vf[(ks << 1) + cb] = *reinterpret_cast<const short8v*>(
            VvB + (((size_t)((cb << 4) + col)) << 12) + mN + (ks << 5) + (hi << 3));
  }

  // ---- merge the two KV-groups + epilogue ----
  if (hi == 0) { Mm[g][(wg << 4) + col] = m_run; Ll[g][(wg << 4) + col] = l_run; }
  __syncthreads();
  float fa[4], fb[4], linv[4];
#pragma unroll
  for (int nc = 0; nc < 4; ++nc) {
    float ma = Mm[0][(nc << 4) + col], mb2 = Mm[1][(nc << 4) + col];
    float mm = fmaxf(ma, mb2);
    float ea = __expf(ma - mm), eb = __expf(mb2 - mm);
    linv[nc] = 1.f / (Ll[0][(nc << 4) + col] * ea + Ll[1][(nc << 4) + col] * eb);
    fa[nc] = ea; fb[nc] = eb;
  }
#pragma unroll
  for (int cb = 0; cb < 2; ++cb) {
    if (g == 1) {
#pragma unroll
      for (int nc = 0; nc < 4; ++nc)
#pragma unroll
        for (int r = 0; r < 4; ++r)
          Ob[wg][(nc << 2) + r][lane] = o_acc[cb][nc][r];
    }
    __syncthreads();
    if (g == 0) {
#pragma unroll
      for (int nc = 0; nc < 4; ++nc)
#pragma unroll
        for (int r = 0; r < 4; ++r) {
          float o = o_acc[cb][nc][r] * fa[nc] + Ob[wg][(nc << 2) + r][lane] * fb[nc];
          int cg = cBase + (cb << 4) + (hi << 2) + r;
          int ng = (qt << 6) + (nc << 4) + col;
          size_t off = (((size_t)((b << 8) + cg)) << 12) + ng;
          out[off] = o * linv[nc] + x[off];
        }
    }
    __syncthreads();
  }
}

// ---------------- launcher ----------------
extern "C" void kernel_launch(void* const* d_in, const int* in_sizes, int n_in,
                              void* d_out, int out_size, void* d_ws, size_t ws_size,
                              hipStream_t stream) {
  (void)in_sizes; (void)n_in; (void)out_size; (void)ws_size;
  const float* x  = (const float*)d_in[0];
  const float* Wq = (const float*)d_in[1];
  const float* Wk = (const float*)d_in[2];
  const float* Wv = (const float*)d_in[3];
  float* out = (float*)d_out;

  unsigned short* Qt = (unsigned short*)d_ws;                      // [B][N][32]  1.05 MB
  unsigned short* Kt = Qt + (size_t)Bn * Nn * CRn;                 // [B][N][32]  1.05 MB
  unsigned short* Vv = Kt + (size_t)Bn * Nn * CRn;                 // [B][C][N]   8.39 MB
  unsigned short* Wb = Vv + (size_t)Bn * Cn * Nn;                  // [320][256]  164 KB

  hipLaunchKernelGGL(k_wcast, dim3(80),        dim3(256), 0, stream, Wq, Wk, Wv, Wb);
  hipLaunchKernelGGL(k_proj,  dim3(64, 4),     dim3(512), 0, stream, Wb, x, Qt, Kt, Vv);
  hipLaunchKernelGGL(k_attn,  dim3(512),       dim3(512), 0, stream, Qt, Kt, Vv, x, out);
}

// Round 8
// 175.230 us; speedup vs baseline: 1.0852x; 1.0852x over previous
//
#include <hip/hip_runtime.h>
#include <stdint.h>
#include <stddef.h>

// Problem: B=4, C=256, CR=32, H=W=64, N=4096
#define Bn 4
#define Cn 256
#define CRn 32
#define Nn 4096

typedef __attribute__((ext_vector_type(8))) short short8v;  // 8 bf16 (4 VGPR)
typedef __attribute__((ext_vector_type(4))) float f32x4;

__device__ __forceinline__ unsigned short f2bf(float f) {
  unsigned int u = __float_as_uint(f);
  u += 0x7FFFu + ((u >> 16) & 1u);   // RNE
  return (unsigned short)(u >> 16);
}

// ---------------- kernel 0: cast W (Wq|Wk|Wv rows) -> Wb [320][256] bf16 ----------------
__global__ void __launch_bounds__(256) k_wcast(const float* __restrict__ Wq,
                                               const float* __restrict__ Wk,
                                               const float* __restrict__ Wv,
                                               unsigned short* __restrict__ Wb) {
  int idx = (blockIdx.x * 256 + threadIdx.x) * 4;   // 80 blocks -> 81920 elems
  int row = idx >> 8, cc = idx & 255;
  const float* src = (row < 32) ? &Wq[row * 256 + cc]
                   : (row < 64) ? &Wk[(row - 32) * 256 + cc]
                                : &Wv[(row - 64) * 256 + cc];
  float4 f = *reinterpret_cast<const float4*>(src);
  ushort4 o;
  o.x = f2bf(f.x); o.y = f2bf(f.y); o.z = f2bf(f.z); o.w = f2bf(f.w);
  *reinterpret_cast<ushort4*>(&Wb[idx]) = o;
}

// ---------------- kernel 1: fused transpose + projections (Wb LDS-staged) ----------------
// grid (nt 64, rt 2, b 4) = 512 blocks, 512 thr. Block handles W-rows rt*160..+160.
// Per block: stage x^T tile [64 n][256 c] bf16 in LDS, then 8 K-steps; each step's
// Wb slice [160][32] staged via global_load_lds (dbuf, source-preswizzled so reads
// are 2-way bank-free).
__global__ void __launch_bounds__(512) k_proj(const unsigned short* __restrict__ Wb,
                                              const float* __restrict__ x,
                                              unsigned short* __restrict__ Qt,
                                              unsigned short* __restrict__ Kt,
                                              unsigned short* __restrict__ V) {
  __shared__ __align__(16) unsigned char smem[54272];
  unsigned short* xs   = (unsigned short*)smem;              // [64 n][264 c] bf16 (33792 B)
  unsigned short* wbuf = (unsigned short*)(smem + 33792);    // 2 x [160][32] bf16 (2x10240 B)
  float*          xf   = (float*)(smem + 33792);             // [64][65] f32 (staging only)
  unsigned short* vb   = (unsigned short*)smem;              // [nch][72] bf16 (epilogue)

  const int t  = threadIdx.x;
  const int nt = blockIdx.x, rt = blockIdx.y, b = blockIdx.z;
  const int rbase = rt * 160;
  const int li = t & 15, cr = t >> 4;

  // ---- stage x^T tile in 4 rounds of 64 channels ----
  for (int ct = 0; ct < 4; ++ct) {
    if (ct) __syncthreads();        // xf reuse
#pragma unroll
    for (int p = 0; p < 2; ++p) {
      int c = cr + (p << 5);
      float4 f = *reinterpret_cast<const float4*>(
          &x[(((size_t)((b << 8) + (ct << 6) + c)) << 12) + (nt << 6) + (li << 2)]);
      xf[c * 65 + (li << 2) + 0] = f.x;
      xf[c * 65 + (li << 2) + 1] = f.y;
      xf[c * 65 + (li << 2) + 2] = f.z;
      xf[c * 65 + (li << 2) + 3] = f.w;
    }
    __syncthreads();
#pragma unroll
    for (int p = 0; p < 2; ++p) {
      int nl = cr + (p << 5);
      int cq = li << 2;
      ushort4 o;
      o.x = f2bf(xf[(cq + 0) * 65 + nl]);
      o.y = f2bf(xf[(cq + 1) * 65 + nl]);
      o.z = f2bf(xf[(cq + 2) * 65 + nl]);
      o.w = f2bf(xf[(cq + 3) * 65 + nl]);
      *reinterpret_cast<ushort4*>(&xs[nl * 264 + (ct << 6) + cq]) = o;
    }
  }
  __syncthreads();   // xf dead from here; wbuf region free

  // Wb slice staging: 640 16B-units: row = idx>>2 (0..159), seg = idx&3.
  // LDS[row][seg] = Wb[rbase+row][ks*32 + (seg ^ fsw(row))*8], fsw = (row^(row>>2))&3
  auto STAGEWB = [&](int ks, int buf) {
#pragma unroll
    for (int r = 0; r < 2; ++r) {
      int idx = (r << 9) + t;
      if (idx < 640) {
        int row = idx >> 2, seg = idx & 3;
        int sseg = seg ^ ((row ^ (row >> 2)) & 3);
        const unsigned short* g =
            Wb + (((size_t)(rbase + row)) << 8) + (ks << 5) + (sseg << 3);
        __builtin_amdgcn_global_load_lds(
            (const __attribute__((address_space(1))) void*)g,
            (__attribute__((address_space(3))) void*)(wbuf + buf * 5120 + idx * 8),
            16, 0, 0);
      }
    }
  };

  STAGEWB(0, 0);
  __syncthreads();

  const int lane = t & 63, w = t >> 6, col = lane & 15, hi = lane >> 4;
  const int nw = w & 3, rh2 = w >> 2;      // n-quarter, row-half (80 rows)
  f32x4 zero4 = {0.f, 0.f, 0.f, 0.f};
  f32x4 acc[5];
#pragma unroll
  for (int rc = 0; rc < 5; ++rc) acc[rc] = zero4;

#pragma unroll 1
  for (int ks = 0; ks < 8; ++ks) {
    const unsigned short* wB = wbuf + (ks & 1) * 5120;
    if (ks < 7) STAGEWB(ks + 1, (ks & 1) ^ 1);
    short8v af = *reinterpret_cast<const short8v*>(
        &xs[((nw << 4) + col) * 264 + (ks << 5) + (hi << 3)]);
#pragma unroll
    for (int rc = 0; rc < 5; ++rc) {
      int row = rh2 * 80 + (rc << 4) + col;
      int sw = hi ^ ((row ^ (row >> 2)) & 3);
      short8v bf = *reinterpret_cast<const short8v*>(wB + row * 32 + (sw << 3));
      acc[rc] = __builtin_amdgcn_mfma_f32_16x16x32_bf16(af, bf, acc[rc], 0, 0, 0);
    }
    __syncthreads();   // drains vmcnt (next-slice gload_lds) + lgkm
  }

  // ---- Q/K outputs (rt==0, rh2==0: W-rows 0..63) ----
  if (rt == 0 && rh2 == 0) {
#pragma unroll
    for (int rc = 0; rc < 2; ++rc)
#pragma unroll
      for (int r = 0; r < 4; ++r) {
        int n = (nt << 6) + (nw << 4) + (hi << 2) + r;
        Qt[(((size_t)((b << 12) + n)) << 5) + (rc << 4) + col] = f2bf(acc[rc][r]);
      }
#pragma unroll
    for (int rc = 2; rc < 4; ++rc)
#pragma unroll
      for (int r = 0; r < 4; ++r) {
        int n = (nt << 6) + (nw << 4) + (hi << 2) + r;
        Kt[(((size_t)((b << 12) + n)) << 5) + ((rc - 2) << 4) + col] = f2bf(acc[rc][r]);
      }
  }

  // ---- V channels -> vb[ch_l][72] (xs dead; alias) ----
  const int nch = rt ? 160 : 96;
  {
    const int nb = (nw << 4) + (hi << 2);
    const int sub = (rt == 0) ? 64 : 0;
#pragma unroll
    for (int rc = 0; rc < 5; ++rc) {
      int grow_l = rh2 * 80 + (rc << 4) + col;     // 0..159 local row
      int ch_l = grow_l - sub;
      if (ch_l >= 0) {
#pragma unroll
        for (int r = 0; r < 4; ++r)
          vb[ch_l * 72 + nb + r] = f2bf(acc[rc][r]);
      }
    }
  }
  __syncthreads();

  // ---- coalesced V store: nch*8 x 16B units ----
  const int cgBase = rt ? 96 : 0;
#pragma unroll
  for (int p = 0; p < 3; ++p) {
    int idx = (p << 9) + t;
    if (idx < nch * 8) {
      int c = idx >> 3, off = idx & 7;
      int offp = off ^ (c & 7);   // LDS bank spread; same 128B global segment
      int4 dv = *reinterpret_cast<const int4*>(&vb[c * 72 + (offp << 3)]);
      *reinterpret_cast<int4*>(
          &V[(((size_t)((b << 8) + cgBase + c)) << 12) + (nt << 6) + (offp << 3)]) = dv;
    }
  }
}

// ---------------- kernel 2: flash attention ----------------
// grid 512 = (b 4) x (ch 2, channel half) x (qt 64). 512 thr, 8 waves.
// wave w: g = w>>2 (KV half: kt in [g*32, g*32+32)), wg = w&3 (softmax cols wg*16..+15,
// channel slice cBase = ch*128 + wg*32). K and V fragments direct from L2 into regs.
// One lgkm-only barrier per phase; Pt/Sc double-buffered by phase parity.
__global__ void __launch_bounds__(512, 2) k_attn(const unsigned short* __restrict__ Qt,
                                                 const unsigned short* __restrict__ Kt,
                                                 const unsigned short* __restrict__ Vv,
                                                 const float* __restrict__ x,
                                                 float* __restrict__ out) {
  __shared__ unsigned short Qs[64][40];
  __shared__ __align__(16) unsigned short Pt[2][2][64 * 64];  // [g][parity], 16B-unit XOR swz
  __shared__ float Sc[2][2][64];
  __shared__ float Mm[2][64], Ll[2][64];
  __shared__ float Ob[4][16][64];

  const int t = threadIdx.x, bx = blockIdx.x;
  const int xcd = bx & 7;                 // XCD-locality: fixed (b,ch) per XCD
  const int b = xcd >> 1, ch = xcd & 1;
  const int qt = bx >> 3;                 // 0..63
  const int lane = t & 63, w = t >> 6, col = lane & 15, hi = lane >> 4;
  const int g = w >> 2, wg = w & 3;
  const int cBase = (ch << 7) + (wg << 5);

  if (t < 256) {  // stage Q tile [64][32]
    const int mr = t >> 2, u = t & 3;
    int4 d = *reinterpret_cast<const int4*>(
        Qt + (((size_t)((b << 12) + (qt << 6) + mr)) << 5) + (u << 3));
    *reinterpret_cast<int4*>(&Qs[mr][u << 3]) = d;
  }

  const unsigned short* KtB = Kt + (((size_t)(b << 12)) << 5);
  const unsigned short* VvB = Vv + (((size_t)((b << 8) + cBase)) << 12);

  const int kt0 = g << 5;
  int m0 = kt0 << 6;
  short8v kf[4], vf[4];
#pragma unroll
  for (int mb = 0; mb < 4; ++mb)
    kf[mb] = *reinterpret_cast<const short8v*>(
        KtB + (((size_t)(m0 + (mb << 4) + col)) << 5) + (hi << 3));
#pragma unroll
  for (int ks = 0; ks < 2; ++ks)
#pragma unroll
    for (int cb = 0; cb < 2; ++cb)
      vf[(ks << 1) + cb] = *reinterpret_cast<const short8v*>(
          VvB + (((size_t)((cb << 4) + col)) << 12) + m0 + (ks << 5) + (hi << 3));
  __syncthreads();
  const short8v qf = *reinterpret_cast<const short8v*>(&Qs[(wg << 4) + col][hi << 3]);

  f32x4 zero4 = {0.f, 0.f, 0.f, 0.f};
  f32x4 o_acc[2][4];
#pragma unroll
  for (int cb = 0; cb < 2; ++cb)
#pragma unroll
    for (int nc = 0; nc < 4; ++nc) o_acc[cb][nc] = zero4;
  float m_run = -3e38f, l_run = 0.f;

#pragma unroll 1
  for (int i = 0; i < 32; ++i) {
    const int p = i & 1;
    const int iNext = (i < 31) ? (i + 1) : 31;
    const int mN = (kt0 + iNext) << 6;

    // ---- S^T slice: rows m (4 chunks), cols n = wg*16..+15 ----
    f32x4 s_acc[4];
#pragma unroll
    for (int mb = 0; mb < 4; ++mb)
      s_acc[mb] = __builtin_amdgcn_mfma_f32_16x16x32_bf16(kf[mb], qf, zero4, 0, 0, 0);
    // K prefetch next tile (WAR on kf orders after the MFMAs)
#pragma unroll
    for (int mb = 0; mb < 4; ++mb)
      kf[mb] = *reinterpret_cast<const short8v*>(
          KtB + (((size_t)(mN + (mb << 4) + col)) << 5) + (hi << 3));

    // ---- wave-local online softmax (column n = qt*64 + wg*16 + col) ----
    float tm = -3e38f;
#pragma unroll
    for (int mb = 0; mb < 4; ++mb)
#pragma unroll
      for (int r = 0; r < 4; ++r) tm = fmaxf(tm, s_acc[mb][r]);
    tm = fmaxf(tm, __shfl_xor(tm, 16));
    tm = fmaxf(tm, __shfl_xor(tm, 32));
    float mn = fmaxf(m_run, tm);
    float sc = __expf(m_run - mn);
    m_run = mn;
    float ps = 0.f;
#pragma unroll
    for (int mb = 0; mb < 4; ++mb)
#pragma unroll
      for (int r = 0; r < 4; ++r) {
        float pv = __expf(s_acc[mb][r] - mn);
        s_acc[mb][r] = pv;
        ps += pv;
      }
    ps += __shfl_xor(ps, 16);
    ps += __shfl_xor(ps, 32);
    l_run = l_run * sc + ps;
    if (hi == 0) Sc[g][p][(wg << 4) + col] = sc;
    // P^T bf16 -> Pt[g][p], rows n-local, 16B-unit XOR swizzle on m
#pragma unroll
    for (int mb = 0; mb < 4; ++mb) {
      uint2 pk2;
      pk2.x = (unsigned)f2bf(s_acc[mb][0]) | ((unsigned)f2bf(s_acc[mb][1]) << 16);
      pk2.y = (unsigned)f2bf(s_acc[mb][2]) | ((unsigned)f2bf(s_acc[mb][3]) << 16);
      int uu = (mb << 1) + (hi >> 1);
      int up = uu ^ (col & 7);
      *reinterpret_cast<uint2*>(
          &Pt[g][p][(((wg << 4) + col) << 6) + (up << 3) + ((hi & 1) << 2)]) = pk2;
    }

    // ---- single barrier: drain LDS writes only; V/K loads stay in flight ----
    asm volatile("s_waitcnt lgkmcnt(0)" ::: "memory");
    __builtin_amdgcn_s_barrier();

    // ---- rescale + PV (Pt[g][p], current vf) ----
    float scl[4];
#pragma unroll
    for (int nc = 0; nc < 4; ++nc) scl[nc] = Sc[g][p][(nc << 4) + col];
#pragma unroll
    for (int cb = 0; cb < 2; ++cb)
#pragma unroll
      for (int nc = 0; nc < 4; ++nc) o_acc[cb][nc] *= scl[nc];
#pragma unroll
    for (int ks = 0; ks < 2; ++ks) {
      short8v pb[4];
      int up2 = ((ks << 2) + hi) ^ (col & 7);
#pragma unroll
      for (int nc = 0; nc < 4; ++nc)
        pb[nc] = *reinterpret_cast<const short8v*>(
            &Pt[g][p][(((nc << 4) + col) << 6) + (up2 << 3)]);
#pragma unroll
      for (int cb = 0; cb < 2; ++cb)
#pragma unroll
        for (int nc = 0; nc < 4; ++nc)
          o_acc[cb][nc] = __builtin_amdgcn_mfma_f32_16x16x32_bf16(
              vf[(ks << 1) + cb], pb[nc], o_acc[cb][nc], 0, 0, 0);
    }
    // V prefetch next tile (WAR on vf orders after the MFMAs; in flight across barrier)
#pragma unroll
    for (int ks = 0; ks < 2; ++ks)
#pragma unroll
      for (int cb = 0; cb < 2; ++cb)
        vf[(ks << 1) + cb] = *reinterpret_cast<const short8v*>(
            VvB + (((size_t)((cb << 4) + col)) << 12) + mN + (ks << 5) + (hi << 3));
  }

  // ---- merge the two KV-groups + epilogue ----
  if (hi == 0) { Mm[g][(wg << 4) + col] = m_run; Ll[g][(wg << 4) + col] = l_run; }
  __syncthreads();
  float fa[4], fb[4], linv[4];
#pragma unroll
  for (int nc = 0; nc < 4; ++nc) {
    float ma = Mm[0][(nc << 4) + col], mb2 = Mm[1][(nc << 4) + col];
    float mm = fmaxf(ma, mb2);
    float ea = __expf(ma - mm), eb = __expf(mb2 - mm);
    linv[nc] = 1.f / (Ll[0][(nc << 4) + col] * ea + Ll[1][(nc << 4) + col] * eb);
    fa[nc] = ea; fb[nc] = eb;
  }
#pragma unroll
  for (int cb = 0; cb < 2; ++cb) {
    if (g == 1) {
#pragma unroll
      for (int nc = 0; nc < 4; ++nc)
#pragma unroll
        for (int r = 0; r < 4; ++r)
          Ob[wg][(nc << 2) + r][lane] = o_acc[cb][nc][r];
    }
    __syncthreads();
    if (g == 0) {
#pragma unroll
      for (int nc = 0; nc < 4; ++nc)
#pragma unroll
        for (int r = 0; r < 4; ++r) {
          float o = o_acc[cb][nc][r] * fa[nc] + Ob[wg][(nc << 2) + r][lane] * fb[nc];
          int cg = cBase + (cb << 4) + (hi << 2) + r;
          int ng = (qt << 6) + (nc << 4) + col;
          size_t off = (((size_t)((b << 8) + cg)) << 12) + ng;
          out[off] = o * linv[nc] + x[off];
        }
    }
    __syncthreads();
  }
}

// ---------------- launcher ----------------
extern "C" void kernel_launch(void* const* d_in, const int* in_sizes, int n_in,
                              void* d_out, int out_size, void* d_ws, size_t ws_size,
                              hipStream_t stream) {
  (void)in_sizes; (void)n_in; (void)out_size; (void)ws_size;
  const float* x  = (const float*)d_in[0];
  const float* Wq = (const float*)d_in[1];
  const float* Wk = (const float*)d_in[2];
  const float* Wv = (const float*)d_in[3];
  float* out = (float*)d_out;

  unsigned short* Qt = (unsigned short*)d_ws;                      // [B][N][32]  1.05 MB
  unsigned short* Kt = Qt + (size_t)Bn * Nn * CRn;                 // [B][N][32]  1.05 MB
  unsigned short* Vv = Kt + (size_t)Bn * Nn * CRn;                 // [B][C][N]   8.39 MB
  unsigned short* Wb = Vv + (size_t)Bn * Cn * Nn;                  // [320][256]  164 KB

  hipLaunchKernelGGL(k_wcast, dim3(80),        dim3(256), 0, stream, Wq, Wk, Wv, Wb);
  hipLaunchKernelGGL(k_proj,  dim3(64, 2, 4),  dim3(512), 0, stream, Wb, x, Qt, Kt, Vv);
  hipLaunchKernelGGL(k_attn,  dim3(512),       dim3(512), 0, stream, Qt, Kt, Vv, x, out);
}